// Round 9
// baseline (364.372 us; speedup 1.0000x reference)
//
#include <hip/hip_runtime.h>
#include <math.h>

#define N_NODES 50000
#define N_EDGES 800000
#define IN_C 16
#define HID_C 16
#define OUT_C 10
#define N_GRAPHS 500
#define EDGE_DIM 3
#define MLP_HID 25
#define BN_EPS 1e-5f

#define SCAN_NB ((N_NODES + 255) / 256)   // 196 blocks

typedef __attribute__((ext_vector_type(8))) short short8;
typedef __attribute__((ext_vector_type(4))) float f32x4;
typedef __attribute__((ext_vector_type(2))) float f32x2;
union U4S8 { uint4 u; short8 s; };

// ---------------- small prep ----------------

// block 0: fold BN into edge-MLP layer-1 -> AC[k][4]={A0,A1,A2,C}, k<25;
// AC[25]={0,0,0,1} so the bias rows of W' get h==relu(1)==1.
// all blocks: goff[g] = lower_bound(batch, g) (batch sorted)
__global__ __launch_bounds__(256) void prep_graph_kernel(
    const float* __restrict__ W1a, const float* __restrict__ b1a,
    const float* __restrict__ g1, const float* __restrict__ bt1,
    const float* __restrict__ m1, const float* __restrict__ v1,
    const float* __restrict__ W2a, const float* __restrict__ b2a,
    const float* __restrict__ g2, const float* __restrict__ bt2,
    const float* __restrict__ m2, const float* __restrict__ v2,
    const int* __restrict__ batch,
    float* __restrict__ AC1, float* __restrict__ AC2,
    int* __restrict__ goff)
{
    int t = threadIdx.x;
    if (blockIdx.x == 0) {
        if (t < 26) {
            int k = t;
            if (k < 25) {
                float sc = g1[k] / sqrtf(v1[k] + BN_EPS);
                AC1[k*4+0] = sc * W1a[0*MLP_HID+k];
                AC1[k*4+1] = sc * W1a[1*MLP_HID+k];
                AC1[k*4+2] = sc * W1a[2*MLP_HID+k];
                AC1[k*4+3] = sc * (b1a[k] - m1[k]) + bt1[k];
            } else {
                AC1[100] = 0.f; AC1[101] = 0.f; AC1[102] = 0.f; AC1[103] = 1.f;
            }
        } else if (t >= 32 && t < 58) {
            int k = t - 32;
            if (k < 25) {
                float sc = g2[k] / sqrtf(v2[k] + BN_EPS);
                AC2[k*4+0] = sc * W2a[0*MLP_HID+k];
                AC2[k*4+1] = sc * W2a[1*MLP_HID+k];
                AC2[k*4+2] = sc * W2a[2*MLP_HID+k];
                AC2[k*4+3] = sc * (b2a[k] - m2[k]) + bt2[k];
            } else {
                AC2[100] = 0.f; AC2[101] = 0.f; AC2[102] = 0.f; AC2[103] = 1.f;
            }
        }
    }
    int g = blockIdx.x * blockDim.x + t;
    if (g <= N_GRAPHS) {
        int lo = 0, hi = N_NODES;
        while (lo < hi) {
            int mid = (lo + hi) >> 1;
            if (batch[mid] < g) lo = mid + 1; else hi = mid;
        }
        goff[g] = lo;
    }
}

// Pack W' = [Wb rows (k'=k*16+i, k<25) ; bb rows (k'=400+i)] (416 x 16) into
// per-MFMA per-lane B-fragments, split hi/lo bf16 (Markidis). Element j of
// (m, lane L): row k' = 32m + 8(L>>4) + j, col o = L&15.
__global__ __launch_bounds__(256) void pack_w_kernel(
    const float* __restrict__ W1b, const float* __restrict__ b1b,
    const float* __restrict__ W2b, const float* __restrict__ b2b,
    unsigned int* __restrict__ WHI1, unsigned int* __restrict__ WLO1,
    unsigned int* __restrict__ WHI2, unsigned int* __restrict__ WLO2)
{
    int t = blockIdx.x * 256 + threadIdx.x;
    if (t >= 1664) return;
    const float *Wb, *bb; unsigned int *WH, *WL;
    int tl = t;
    if (t < 832) { Wb = W1b; bb = b1b; WH = WHI1; WL = WLO1; }
    else { tl = t - 832; Wb = W2b; bb = b2b; WH = WHI2; WL = WLO2; }
    int m = tl >> 6;
    int L = tl & 63;
    int q = L >> 4, o = L & 15;
    unsigned int hi[8], lo[8];
    for (int j = 0; j < 8; ++j) {
        int kp = m*32 + q*8 + j;          // 0..415
        int k = kp >> 4, i = kp & 15;
        float w = (k < 25) ? Wb[k*256 + i*16 + o] : bb[i*16 + o];
        unsigned int u = __float_as_uint(w);
        unsigned int h = (u + 0x7FFFu + ((u >> 16) & 1u)) >> 16;   // bf16 RNE
        hi[j] = h;
        float rl = w - __uint_as_float(h << 16);
        unsigned int ul = __float_as_uint(rl);
        lo[j] = (ul + 0x7FFFu + ((ul >> 16) & 1u)) >> 16;
    }
    int base = (m*64 + L) * 4;
    for (int d = 0; d < 4; ++d) {
        WH[base + d] = hi[2*d] | (hi[2*d+1] << 16);
        WL[base + d] = lo[2*d] | (lo[2*d+1] << 16);
    }
}

// ---------------- CSR build (one atomic pass + parallel scan) ----------------

__global__ __launch_bounds__(256) void rank_kernel(const int* __restrict__ dst,
                                                   int* __restrict__ cnt,
                                                   int* __restrict__ rank) {
    int e = blockIdx.x * blockDim.x + threadIdx.x;
    if (e < N_EDGES) rank[e] = atomicAdd(&cnt[dst[e]], 1);
}

__global__ __launch_bounds__(256) void scan_p1(const int* __restrict__ cnt,
                                               int* __restrict__ bsum) {
    __shared__ int lds[256];
    int t = threadIdx.x;
    int idx = blockIdx.x * 256 + t;
    lds[t] = (idx < N_NODES) ? cnt[idx] : 0;
    __syncthreads();
    for (int d = 128; d > 0; d >>= 1) {
        if (t < d) lds[t] += lds[t + d];
        __syncthreads();
    }
    if (t == 0) bsum[blockIdx.x] = lds[0];
}

__global__ __launch_bounds__(256) void scan_p2(const int* __restrict__ bsum,
                                               int* __restrict__ bpre,
                                               int* __restrict__ off) {
    __shared__ int lds[256];
    int t = threadIdx.x;
    lds[t] = (t < SCAN_NB) ? bsum[t] : 0;
    __syncthreads();
    for (int d = 1; d < 256; d <<= 1) {
        int v = (t >= d) ? lds[t - d] : 0;
        __syncthreads();
        lds[t] += v;
        __syncthreads();
    }
    if (t < SCAN_NB) bpre[t] = (t > 0) ? lds[t - 1] : 0;
    if (t == 255) off[N_NODES] = lds[255];
}

__global__ __launch_bounds__(256) void scan_p3(const int* __restrict__ cnt,
                                               const int* __restrict__ bpre,
                                               int* __restrict__ off) {
    __shared__ int lds[256];
    int t = threadIdx.x;
    int idx = blockIdx.x * 256 + t;
    int v = (idx < N_NODES) ? cnt[idx] : 0;
    lds[t] = v;
    __syncthreads();
    for (int d = 1; d < 256; d <<= 1) {
        int u = (t >= d) ? lds[t - d] : 0;
        __syncthreads();
        lds[t] += u;
        __syncthreads();
    }
    if (idx < N_NODES) off[idx] = bpre[blockIdx.x] + lds[t] - v;
}

// rank[e] <- off[dst[e]] + rank[e]  (in-place: rank becomes the CSR slot P[e];
// removes dst/rank/off reads from BOTH hot edge dispatches)
__global__ __launch_bounds__(256) void pos2_kernel(const int* __restrict__ dst,
                                                   const int* __restrict__ off,
                                                   int* __restrict__ rank) {
    int e = blockIdx.x * blockDim.x + threadIdx.x;
    if (e < N_EDGES) rank[e] = off[dst[e]] + rank[e];
}

// ---------------- hot path: MFMA edge kernel, 4 tiles/wave pipelined --------

__device__ __forceinline__ U4S8 packH(float h, float4 xl, float4 xh) {
    f32x2 h2; h2.x = h; h2.y = h;
    f32x2 m0; m0.x = xl.x; m0.y = xl.y; m0 *= h2;
    f32x2 m1; m1.x = xl.z; m1.y = xl.w; m1 *= h2;
    f32x2 m2; m2.x = xh.x; m2.y = xh.y; m2 *= h2;
    f32x2 m3; m3.x = xh.z; m3.y = xh.w; m3 *= h2;
    U4S8 r;
    r.u.x = __builtin_amdgcn_perm(__float_as_uint(m0.y), __float_as_uint(m0.x), 0x07060302u);
    r.u.y = __builtin_amdgcn_perm(__float_as_uint(m1.y), __float_as_uint(m1.x), 0x07060302u);
    r.u.z = __builtin_amdgcn_perm(__float_as_uint(m2.y), __float_as_uint(m2.x), 0x07060302u);
    r.u.w = __builtin_amdgcn_perm(__float_as_uint(m3.y), __float_as_uint(m3.x), 0x07060302u);
    return r;
}

// Per wave: 4 tiles of 16 edges (64 edges), 2-deep software pipeline.
// msg[16e x 16o] = H[16e x 416] @ W'[416 x 16o]; H[e][k'] = h[e][k'>>4] *
// xs[e][k'&15] formed on the fly (A-frag lane L: e=L&15, k'=32m+8q+j ->
// k=2m+(q>>1), i-slice i0=(q&1)*8). W split hi/lo bf16 chained into one fp32
// acc. WHI stationary in VGPRs; WLO in LDS (13.3KB/tile = 104 LDS-cyc/tile
// vs ~400 cyc compute -> not LDS-bound). No per-tile LDS staging: xs straight
// from global (L1), CSR slot = one broadcast uint4 from precomputed P.
__global__ __launch_bounds__(256) void edge_mfma2_kernel(
    const float* __restrict__ xin,
    const int* __restrict__ src,
    const int* __restrict__ P,
    const float* __restrict__ eattr,
    const float* __restrict__ AC,
    const unsigned int* __restrict__ WHI, const unsigned int* __restrict__ WLO,
    float* __restrict__ msg_buf)
{
    __shared__ uint4 wlo_s[832];                         // 13312 B
    __shared__ float ac_s[104];                          //   416 B
    const int tid = threadIdx.x;
    #pragma unroll
    for (int it = 0; it < 4; ++it) {
        int gi = tid + it*256;
        if (gi < 832) wlo_s[gi] = ((const uint4*)WLO)[gi];
    }
    if (tid < 104) ac_s[tid] = AC[tid];
    __syncthreads();

    const int wave = tid >> 6;
    const int lane = tid & 63;
    const int q    = lane >> 4;
    const int el   = lane & 15;
    const int i0   = (q & 1) * 8;

    // stationary W_hi fragments (13 x 4 VGPRs)
    short8 whi[13];
    #pragma unroll
    for (int m = 0; m < 13; ++m) {
        U4S8 c; c.u = ((const uint4*)WHI)[m*64 + lane];
        whi[m] = c.s;
    }

    const int We = blockIdx.x * 256 + wave * 64;   // wave's 64 edges

    // stage all per-tile scalars up front (src, attrs, CSR slots)
    int   ss[4]; float ax[4], ay[4], az[4]; uint4 pp[4];
    #pragma unroll
    for (int t = 0; t < 4; ++t) {
        int e = We + t*16 + el;
        ss[t] = src[e];
        ax[t] = eattr[(size_t)e*3+0];
        ay[t] = eattr[(size_t)e*3+1];
        az[t] = eattr[(size_t)e*3+2];
        pp[t] = *(const uint4*)(P + We + t*16 + q*4);   // rows q*4+r, 16B aligned
    }

    // prime the xs pipeline (gather depends on ss[0])
    float4 xl, xh;
    {
        const float4* xp = (const float4*)(xin + (size_t)ss[0]*16 + i0);
        xl = xp[0]; xh = xp[1];
    }

    #pragma unroll
    for (int t = 0; t < 4; ++t) {
        float4 nxl, nxh;
        if (t < 3) {   // prefetch next tile's xs; flight hidden under compute
            const float4* xp = (const float4*)(xin + (size_t)ss[t+1]*16 + i0);
            nxl = xp[0]; nxh = xp[1];
        }

        f32x4 acc = {0.f, 0.f, 0.f, 0.f};
        #pragma unroll
        for (int m = 0; m < 13; ++m) {
            int k = 2*m + (q >> 1);
            const float4 Ak = *(const float4*)&ac_s[k*4];
            U4S8 wl; wl.u = wlo_s[m*64 + lane];
            float h = fmaxf(fmaf(az[t], Ak.z, fmaf(ay[t], Ak.y,
                              fmaf(ax[t], Ak.x, Ak.w))), 0.f);
            U4S8 hf = packH(h, xl, xh);
            acc = __builtin_amdgcn_mfma_f32_16x16x32_bf16(hf.s, whi[m], acc, 0, 0, 0);
            acc = __builtin_amdgcn_mfma_f32_16x16x32_bf16(hf.s, wl.s,   acc, 0, 0, 0);
        }

        // D layout: col o = el, row = q*4 + r -> slots pp[t].{x,y,z,w}
        msg_buf[(size_t)((unsigned)pp[t].x) * HID_C + el] = acc[0];
        msg_buf[(size_t)((unsigned)pp[t].y) * HID_C + el] = acc[1];
        msg_buf[(size_t)((unsigned)pp[t].z) * HID_C + el] = acc[2];
        msg_buf[(size_t)((unsigned)pp[t].w) * HID_C + el] = acc[3];

        xl = nxl; xh = nxh;
    }
}

// 16 threads per node (lane = out channel). Segment-sum msg_buf rows
// [off[n], off[n+1]) -> mean -> + x@root + bias -> ELU.
__global__ __launch_bounds__(256) void node_gather_kernel(
    const float* __restrict__ xin, const float* __restrict__ msg_buf,
    const int* __restrict__ off,
    const float* __restrict__ root, const float* __restrict__ bias,
    float* __restrict__ xout)
{
    int t = blockIdx.x * blockDim.x + threadIdx.x;
    int n = t >> 4;
    int o = t & 15;
    if (n >= N_NODES) return;
    int lo = off[n], hi = off[n+1];
    float inv = 1.f / fmaxf((float)(hi - lo), 1.f);

    float s0 = 0.f, s1 = 0.f, s2 = 0.f, s3 = 0.f;
    int r = lo;
    for (; r + 4 <= hi; r += 4) {
        s0 += msg_buf[(size_t)r     * HID_C + o];
        s1 += msg_buf[(size_t)(r+1) * HID_C + o];
        s2 += msg_buf[(size_t)(r+2) * HID_C + o];
        s3 += msg_buf[(size_t)(r+3) * HID_C + o];
    }
    for (; r < hi; ++r) s0 += msg_buf[(size_t)r * HID_C + o];
    float s = (s0 + s1) + (s2 + s3);

    float acc = fmaf(s, inv, bias[o]);
    const float* xr = xin + (size_t)n * IN_C;
    #pragma unroll
    for (int i = 0; i < IN_C; ++i)
        acc = fmaf(xr[i], root[i*HID_C+o], acc);
    xout[(size_t)n*HID_C + o] = acc > 0.f ? acc : (expf(acc) - 1.f);
}

// fused: global mean pool (batch sorted -> contiguous segments) + final linear
__global__ __launch_bounds__(64) void pool_final_kernel(
    const float* __restrict__ xin, const int* __restrict__ goff,
    const float* __restrict__ fcW, const float* __restrict__ fcb,
    float* __restrict__ out)
{
    __shared__ float part[4][HID_C];
    __shared__ float pooled[HID_C];
    int g = blockIdx.x;
    int t = threadIdx.x;
    int c = t & 15, sub = t >> 4;
    int lo = goff[g], hi = goff[g+1];
    float s = 0.f;
    for (int n = lo + sub; n < hi; n += 4)
        s += xin[(size_t)n*HID_C + c];
    part[sub][c] = s;
    __syncthreads();
    if (t < HID_C) {
        pooled[t] = (part[0][t] + part[1][t] + part[2][t] + part[3][t])
                    / fmaxf((float)(hi - lo), 1.f);
    }
    __syncthreads();
    if (t < OUT_C) {
        float acc = fcb[t];
        #pragma unroll
        for (int i = 0; i < HID_C; ++i)
            acc = fmaf(pooled[i], fcW[i*OUT_C+t], acc);
        out[g*OUT_C + t] = acc;
    }
}

// ---------------- launch ----------------

extern "C" void kernel_launch(void* const* d_in, const int* in_sizes, int n_in,
                              void* d_out, int out_size, void* d_ws, size_t ws_size,
                              hipStream_t stream)
{
    const float* x     = (const float*)d_in[0];
    const int*   ei    = (const int*)d_in[1];
    const float* eattr = (const float*)d_in[2];
    const int*   batch = (const int*)d_in[3];
    const float* W1a   = (const float*)d_in[4];
    const float* b1a   = (const float*)d_in[5];
    const float* g1    = (const float*)d_in[6];
    const float* bt1   = (const float*)d_in[7];
    const float* m1    = (const float*)d_in[8];
    const float* v1    = (const float*)d_in[9];
    const float* W1b   = (const float*)d_in[10];
    const float* b1b   = (const float*)d_in[11];
    const float* root1 = (const float*)d_in[12];
    const float* bias1 = (const float*)d_in[13];
    const float* W2a   = (const float*)d_in[14];
    const float* b2a   = (const float*)d_in[15];
    const float* g2    = (const float*)d_in[16];
    const float* bt2   = (const float*)d_in[17];
    const float* m2    = (const float*)d_in[18];
    const float* v2    = (const float*)d_in[19];
    const float* W2b   = (const float*)d_in[20];
    const float* b2b   = (const float*)d_in[21];
    const float* root2 = (const float*)d_in[22];
    const float* bias2 = (const float*)d_in[23];
    const float* fcW   = (const float*)d_in[24];
    const float* fcb   = (const float*)d_in[25];

    const int* src = ei;
    const int* dst = ei + N_EDGES;

    float* ws   = (float*)d_ws;
    float* MSG  = ws;                                   // 12,800,000 f
    float* X1   = ws + 12800000;                        //    800,000 f
    float* X2   = ws + 13600000;                        //    800,000 f
    int*   RANK = (int*)(ws + 14400000);                //    800,000 i (becomes P)
    int*   CNT  = (int*)(ws + 15200000);                //     50,000 i
    int*   OFF  = (int*)(ws + 15250000);                //     50,001 i (+pad)
    int*   GOFF = (int*)(ws + 15300064);                //        501 i (+pad)
    unsigned int* WHI1 = (unsigned int*)(ws + 15300576);//      3,328 u (16B aligned)
    unsigned int* WLO1 = (unsigned int*)(ws + 15303904);//      3,328 u
    unsigned int* WHI2 = (unsigned int*)(ws + 15307232);//      3,328 u
    unsigned int* WLO2 = (unsigned int*)(ws + 15310560);//      3,328 u
    float* AC1  = ws + 15313888;                        //        104 f (+pad)
    float* AC2  = ws + 15314000;                        //        104 f
    int*   BSUM = (int*)(ws + 15314112);                //        196 i (+pad)
    int*   BPRE = (int*)(ws + 15314368);                //        196 i
    // total ~15,314,564 f = 61.26 MB

    hipMemsetAsync(CNT, 0, N_NODES * sizeof(int), stream);
    prep_graph_kernel<<<3, 256, 0, stream>>>(W1a, b1a, g1, bt1, m1, v1,
                                             W2a, b2a, g2, bt2, m2, v2,
                                             batch, AC1, AC2, GOFF);
    pack_w_kernel<<<7, 256, 0, stream>>>(W1b, b1b, W2b, b2b,
                                         WHI1, WLO1, WHI2, WLO2);
    rank_kernel<<<N_EDGES/256, 256, 0, stream>>>(dst, CNT, RANK);
    scan_p1<<<SCAN_NB, 256, 0, stream>>>(CNT, BSUM);
    scan_p2<<<1, 256, 0, stream>>>(BSUM, BPRE, OFF);
    scan_p3<<<SCAN_NB, 256, 0, stream>>>(CNT, BPRE, OFF);
    pos2_kernel<<<N_EDGES/256, 256, 0, stream>>>(dst, OFF, RANK);   // RANK -> P

    edge_mfma2_kernel<<<N_EDGES/256, 256, 0, stream>>>(x, src, RANK, eattr,
                                                       AC1, WHI1, WLO1, MSG);
    node_gather_kernel<<<(N_NODES*16+255)/256, 256, 0, stream>>>(x, MSG, OFF,
                                                                 root1, bias1, X1);

    edge_mfma2_kernel<<<N_EDGES/256, 256, 0, stream>>>(X1, src, RANK, eattr,
                                                       AC2, WHI2, WLO2, MSG);
    node_gather_kernel<<<(N_NODES*16+255)/256, 256, 0, stream>>>(X1, MSG, OFF,
                                                                 root2, bias2, X2);

    pool_final_kernel<<<N_GRAPHS, 64, 0, stream>>>(X2, GOFF, fcW, fcb, (float*)d_out);
}

// Round 10
// 310.357 us; speedup vs baseline: 1.1740x; 1.1740x over previous
//
#include <hip/hip_runtime.h>
#include <math.h>

#define N_NODES 50000
#define N_EDGES 800000
#define IN_C 16
#define HID_C 16
#define OUT_C 10
#define N_GRAPHS 500
#define EDGE_DIM 3
#define MLP_HID 25
#define BN_EPS 1e-5f

#define SCAN_NB ((N_NODES + 255) / 256)   // 196 blocks

typedef __attribute__((ext_vector_type(8))) short short8;
typedef __attribute__((ext_vector_type(4))) float f32x4;
typedef __attribute__((ext_vector_type(2))) float f32x2;
union U4S8 { uint4 u; short8 s; };

// ---------------- small prep ----------------

// block 0: fold BN into edge-MLP layer-1 -> AC[k][4]={A0,A1,A2,C}, k<25;
// AC[25]={0,0,0,1} so the bias rows of W' get h==relu(1)==1.
// all blocks: goff[g] = lower_bound(batch, g) (batch sorted)
__global__ __launch_bounds__(256) void prep_graph_kernel(
    const float* __restrict__ W1a, const float* __restrict__ b1a,
    const float* __restrict__ g1, const float* __restrict__ bt1,
    const float* __restrict__ m1, const float* __restrict__ v1,
    const float* __restrict__ W2a, const float* __restrict__ b2a,
    const float* __restrict__ g2, const float* __restrict__ bt2,
    const float* __restrict__ m2, const float* __restrict__ v2,
    const int* __restrict__ batch,
    float* __restrict__ AC1, float* __restrict__ AC2,
    int* __restrict__ goff)
{
    int t = threadIdx.x;
    if (blockIdx.x == 0) {
        if (t < 26) {
            int k = t;
            if (k < 25) {
                float sc = g1[k] / sqrtf(v1[k] + BN_EPS);
                AC1[k*4+0] = sc * W1a[0*MLP_HID+k];
                AC1[k*4+1] = sc * W1a[1*MLP_HID+k];
                AC1[k*4+2] = sc * W1a[2*MLP_HID+k];
                AC1[k*4+3] = sc * (b1a[k] - m1[k]) + bt1[k];
            } else {
                AC1[100] = 0.f; AC1[101] = 0.f; AC1[102] = 0.f; AC1[103] = 1.f;
            }
        } else if (t >= 32 && t < 58) {
            int k = t - 32;
            if (k < 25) {
                float sc = g2[k] / sqrtf(v2[k] + BN_EPS);
                AC2[k*4+0] = sc * W2a[0*MLP_HID+k];
                AC2[k*4+1] = sc * W2a[1*MLP_HID+k];
                AC2[k*4+2] = sc * W2a[2*MLP_HID+k];
                AC2[k*4+3] = sc * (b2a[k] - m2[k]) + bt2[k];
            } else {
                AC2[100] = 0.f; AC2[101] = 0.f; AC2[102] = 0.f; AC2[103] = 1.f;
            }
        }
    }
    int g = blockIdx.x * blockDim.x + t;
    if (g <= N_GRAPHS) {
        int lo = 0, hi = N_NODES;
        while (lo < hi) {
            int mid = (lo + hi) >> 1;
            if (batch[mid] < g) lo = mid + 1; else hi = mid;
        }
        goff[g] = lo;
    }
}

// Pack W' = [Wb rows (k'=k*16+i, k<25) ; bb rows (k'=400+i)] (416 x 16) into
// per-MFMA per-lane B-fragments, single bf16 with RNE (no Markidis split:
// RNE-W error ~0.2% rel, combined with H-trunc stays well under threshold).
// Element j of (m, lane L): row k' = 32m + 8(L>>4) + j, col o = L&15.
__global__ __launch_bounds__(256) void pack_w_kernel(
    const float* __restrict__ W1b, const float* __restrict__ b1b,
    const float* __restrict__ W2b, const float* __restrict__ b2b,
    unsigned int* __restrict__ WHI1, unsigned int* __restrict__ WHI2)
{
    int t = blockIdx.x * 256 + threadIdx.x;
    if (t >= 1664) return;
    const float *Wb, *bb; unsigned int *WH;
    int tl = t;
    if (t < 832) { Wb = W1b; bb = b1b; WH = WHI1; }
    else { tl = t - 832; Wb = W2b; bb = b2b; WH = WHI2; }
    int m = tl >> 6;
    int L = tl & 63;
    int q = L >> 4, o = L & 15;
    unsigned int hi[8];
    for (int j = 0; j < 8; ++j) {
        int kp = m*32 + q*8 + j;          // 0..415
        int k = kp >> 4, i = kp & 15;
        float w = (k < 25) ? Wb[k*256 + i*16 + o] : bb[i*16 + o];
        unsigned int u = __float_as_uint(w);
        hi[j] = (u + 0x7FFFu + ((u >> 16) & 1u)) >> 16;   // bf16 RNE
    }
    int base = (m*64 + L) * 4;
    for (int d = 0; d < 4; ++d)
        WH[base + d] = hi[2*d] | (hi[2*d+1] << 16);
}

// ---------------- CSR build (one atomic pass + parallel scan) ----------------

__global__ __launch_bounds__(256) void rank_kernel(const int* __restrict__ dst,
                                                   int* __restrict__ cnt,
                                                   int* __restrict__ rank) {
    int e = blockIdx.x * blockDim.x + threadIdx.x;
    if (e < N_EDGES) rank[e] = atomicAdd(&cnt[dst[e]], 1);
}

__global__ __launch_bounds__(256) void scan_p1(const int* __restrict__ cnt,
                                               int* __restrict__ bsum) {
    __shared__ int lds[256];
    int t = threadIdx.x;
    int idx = blockIdx.x * 256 + t;
    lds[t] = (idx < N_NODES) ? cnt[idx] : 0;
    __syncthreads();
    for (int d = 128; d > 0; d >>= 1) {
        if (t < d) lds[t] += lds[t + d];
        __syncthreads();
    }
    if (t == 0) bsum[blockIdx.x] = lds[0];
}

__global__ __launch_bounds__(256) void scan_p2(const int* __restrict__ bsum,
                                               int* __restrict__ bpre,
                                               int* __restrict__ off) {
    __shared__ int lds[256];
    int t = threadIdx.x;
    lds[t] = (t < SCAN_NB) ? bsum[t] : 0;
    __syncthreads();
    for (int d = 1; d < 256; d <<= 1) {
        int v = (t >= d) ? lds[t - d] : 0;
        __syncthreads();
        lds[t] += v;
        __syncthreads();
    }
    if (t < SCAN_NB) bpre[t] = (t > 0) ? lds[t - 1] : 0;
    if (t == 255) off[N_NODES] = lds[255];
}

__global__ __launch_bounds__(256) void scan_p3(const int* __restrict__ cnt,
                                               const int* __restrict__ bpre,
                                               int* __restrict__ off) {
    __shared__ int lds[256];
    int t = threadIdx.x;
    int idx = blockIdx.x * 256 + t;
    int v = (idx < N_NODES) ? cnt[idx] : 0;
    lds[t] = v;
    __syncthreads();
    for (int d = 1; d < 256; d <<= 1) {
        int u = (t >= d) ? lds[t - d] : 0;
        __syncthreads();
        lds[t] += u;
        __syncthreads();
    }
    if (idx < N_NODES) off[idx] = bpre[blockIdx.x] + lds[t] - v;
}

// rank[e] <- off[dst[e]] + rank[e]  (in-place: rank becomes the CSR slot P[e])
__global__ __launch_bounds__(256) void pos2_kernel(const int* __restrict__ dst,
                                                   const int* __restrict__ off,
                                                   int* __restrict__ rank) {
    int e = blockIdx.x * blockDim.x + threadIdx.x;
    if (e < N_EDGES) rank[e] = off[dst[e]] + rank[e];
}

// ---------------- hot path: lean MFMA edge kernel ----------------

__device__ __forceinline__ U4S8 packH(float h, float4 xl, float4 xh) {
    f32x2 h2; h2.x = h; h2.y = h;
    f32x2 m0; m0.x = xl.x; m0.y = xl.y; m0 *= h2;
    f32x2 m1; m1.x = xl.z; m1.y = xl.w; m1 *= h2;
    f32x2 m2; m2.x = xh.x; m2.y = xh.y; m2 *= h2;
    f32x2 m3; m3.x = xh.z; m3.y = xh.w; m3 *= h2;
    U4S8 r;
    r.u.x = __builtin_amdgcn_perm(__float_as_uint(m0.y), __float_as_uint(m0.x), 0x07060302u);
    r.u.y = __builtin_amdgcn_perm(__float_as_uint(m1.y), __float_as_uint(m1.x), 0x07060302u);
    r.u.z = __builtin_amdgcn_perm(__float_as_uint(m2.y), __float_as_uint(m2.x), 0x07060302u);
    r.u.w = __builtin_amdgcn_perm(__float_as_uint(m3.y), __float_as_uint(m3.x), 0x07060302u);
    return r;
}

// Per wave: 16 edges, ONE 13-step MFMA chain, no LDS, no barriers, no Markidis
// split. msg[16e x 16o] = H[16e x 416] @ W'[416 x 16o]; H[e][k'] =
// h[e][k'>>4]*xs[e][k'&15] formed on the fly (A-frag lane L: e=L&15,
// k'=32m+8q+j -> k=2m+(q>>1), i-slice i0=(q&1)*8). W single bf16 (RNE).
// unroll 1: whi/AC fragments loaded just-in-time from the 13KB L1-hot WHI
// table instead of pinned in 52 VGPRs (R9's 144-VGPR occupancy collapse).
// 50k thin waves -> latency hidden by occupancy, not per-thread ILP.
__global__ __launch_bounds__(256) void edge_mfma3_kernel(
    const float* __restrict__ xin,
    const int* __restrict__ src,
    const int* __restrict__ P,
    const float* __restrict__ eattr,
    const float* __restrict__ AC,
    const unsigned int* __restrict__ WHI,
    float* __restrict__ msg_buf)
{
    const int tid  = threadIdx.x;
    const int wave = tid >> 6;
    const int lane = tid & 63;
    const int q    = lane >> 4;
    const int el   = lane & 15;
    const int i0   = (q & 1) * 8;
    const int b    = q >> 1;
    const int e0   = (blockIdx.x * 4 + wave) * 16;
    const int e    = e0 + el;

    const int s = src[e];
    const float a0 = eattr[(size_t)e*3+0];
    const float a1 = eattr[(size_t)e*3+1];
    const float a2 = eattr[(size_t)e*3+2];
    const uint4 pp = *(const uint4*)(P + e0 + q*4);   // D rows q*4+r
    const float4* xp = (const float4*)(xin + (size_t)s*16 + i0);
    const float4 xl = xp[0], xh = xp[1];

    f32x4 acc = {0.f, 0.f, 0.f, 0.f};
    #pragma unroll 1
    for (int m = 0; m < 13; ++m) {
        const float4 Ak = *(const float4*)(AC + (2*m + b)*4);   // L1-hot
        U4S8 w; w.u = ((const uint4*)WHI)[m*64 + lane];          // L1-hot
        float h = fmaxf(fmaf(a2, Ak.z, fmaf(a1, Ak.y, fmaf(a0, Ak.x, Ak.w))), 0.f);
        U4S8 hf = packH(h, xl, xh);
        acc = __builtin_amdgcn_mfma_f32_16x16x32_bf16(hf.s, w.s, acc, 0, 0, 0);
    }

    // D layout: col o = el, row = q*4 + r
    msg_buf[(size_t)((unsigned)pp.x) * HID_C + el] = acc[0];
    msg_buf[(size_t)((unsigned)pp.y) * HID_C + el] = acc[1];
    msg_buf[(size_t)((unsigned)pp.z) * HID_C + el] = acc[2];
    msg_buf[(size_t)((unsigned)pp.w) * HID_C + el] = acc[3];
}

// 16 threads per node (lane = out channel). Segment-sum msg_buf rows
// [off[n], off[n+1]) -> mean -> + x@root + bias -> ELU.
__global__ __launch_bounds__(256) void node_gather_kernel(
    const float* __restrict__ xin, const float* __restrict__ msg_buf,
    const int* __restrict__ off,
    const float* __restrict__ root, const float* __restrict__ bias,
    float* __restrict__ xout)
{
    int t = blockIdx.x * blockDim.x + threadIdx.x;
    int n = t >> 4;
    int o = t & 15;
    if (n >= N_NODES) return;
    int lo = off[n], hi = off[n+1];
    float inv = 1.f / fmaxf((float)(hi - lo), 1.f);

    float s0 = 0.f, s1 = 0.f, s2 = 0.f, s3 = 0.f;
    int r = lo;
    for (; r + 4 <= hi; r += 4) {
        s0 += msg_buf[(size_t)r     * HID_C + o];
        s1 += msg_buf[(size_t)(r+1) * HID_C + o];
        s2 += msg_buf[(size_t)(r+2) * HID_C + o];
        s3 += msg_buf[(size_t)(r+3) * HID_C + o];
    }
    for (; r < hi; ++r) s0 += msg_buf[(size_t)r * HID_C + o];
    float s = (s0 + s1) + (s2 + s3);

    float acc = fmaf(s, inv, bias[o]);
    const float* xr = xin + (size_t)n * IN_C;
    #pragma unroll
    for (int i = 0; i < IN_C; ++i)
        acc = fmaf(xr[i], root[i*HID_C+o], acc);
    xout[(size_t)n*HID_C + o] = acc > 0.f ? acc : (expf(acc) - 1.f);
}

// fused: global mean pool (batch sorted -> contiguous segments) + final linear
__global__ __launch_bounds__(64) void pool_final_kernel(
    const float* __restrict__ xin, const int* __restrict__ goff,
    const float* __restrict__ fcW, const float* __restrict__ fcb,
    float* __restrict__ out)
{
    __shared__ float part[4][HID_C];
    __shared__ float pooled[HID_C];
    int g = blockIdx.x;
    int t = threadIdx.x;
    int c = t & 15, sub = t >> 4;
    int lo = goff[g], hi = goff[g+1];
    float s = 0.f;
    for (int n = lo + sub; n < hi; n += 4)
        s += xin[(size_t)n*HID_C + c];
    part[sub][c] = s;
    __syncthreads();
    if (t < HID_C) {
        pooled[t] = (part[0][t] + part[1][t] + part[2][t] + part[3][t])
                    / fmaxf((float)(hi - lo), 1.f);
    }
    __syncthreads();
    if (t < OUT_C) {
        float acc = fcb[t];
        #pragma unroll
        for (int i = 0; i < HID_C; ++i)
            acc = fmaf(pooled[i], fcW[i*OUT_C+t], acc);
        out[g*OUT_C + t] = acc;
    }
}

// ---------------- launch ----------------

extern "C" void kernel_launch(void* const* d_in, const int* in_sizes, int n_in,
                              void* d_out, int out_size, void* d_ws, size_t ws_size,
                              hipStream_t stream)
{
    const float* x     = (const float*)d_in[0];
    const int*   ei    = (const int*)d_in[1];
    const float* eattr = (const float*)d_in[2];
    const int*   batch = (const int*)d_in[3];
    const float* W1a   = (const float*)d_in[4];
    const float* b1a   = (const float*)d_in[5];
    const float* g1    = (const float*)d_in[6];
    const float* bt1   = (const float*)d_in[7];
    const float* m1    = (const float*)d_in[8];
    const float* v1    = (const float*)d_in[9];
    const float* W1b   = (const float*)d_in[10];
    const float* b1b   = (const float*)d_in[11];
    const float* root1 = (const float*)d_in[12];
    const float* bias1 = (const float*)d_in[13];
    const float* W2a   = (const float*)d_in[14];
    const float* b2a   = (const float*)d_in[15];
    const float* g2    = (const float*)d_in[16];
    const float* bt2   = (const float*)d_in[17];
    const float* m2    = (const float*)d_in[18];
    const float* v2    = (const float*)d_in[19];
    const float* W2b   = (const float*)d_in[20];
    const float* b2b   = (const float*)d_in[21];
    const float* root2 = (const float*)d_in[22];
    const float* bias2 = (const float*)d_in[23];
    const float* fcW   = (const float*)d_in[24];
    const float* fcb   = (const float*)d_in[25];

    const int* src = ei;
    const int* dst = ei + N_EDGES;

    float* ws   = (float*)d_ws;
    float* MSG  = ws;                                   // 12,800,000 f
    float* X1   = ws + 12800000;                        //    800,000 f
    float* X2   = ws + 13600000;                        //    800,000 f
    int*   RANK = (int*)(ws + 14400000);                //    800,000 i (becomes P)
    int*   CNT  = (int*)(ws + 15200000);                //     50,000 i
    int*   OFF  = (int*)(ws + 15250000);                //     50,001 i (+pad)
    int*   GOFF = (int*)(ws + 15300064);                //        501 i (+pad)
    unsigned int* WHI1 = (unsigned int*)(ws + 15300576);//      3,328 u (16B aligned)
    unsigned int* WHI2 = (unsigned int*)(ws + 15303904);//      3,328 u
    float* AC1  = ws + 15307232;                        //        104 f (+pad)
    float* AC2  = ws + 15307344;                        //        104 f
    int*   BSUM = (int*)(ws + 15307456);                //        196 i (+pad)
    int*   BPRE = (int*)(ws + 15307712);                //        196 i
    // total ~15,307,908 f = 61.23 MB

    hipMemsetAsync(CNT, 0, N_NODES * sizeof(int), stream);
    prep_graph_kernel<<<3, 256, 0, stream>>>(W1a, b1a, g1, bt1, m1, v1,
                                             W2a, b2a, g2, bt2, m2, v2,
                                             batch, AC1, AC2, GOFF);
    pack_w_kernel<<<7, 256, 0, stream>>>(W1b, b1b, W2b, b2b, WHI1, WHI2);
    rank_kernel<<<N_EDGES/256, 256, 0, stream>>>(dst, CNT, RANK);
    scan_p1<<<SCAN_NB, 256, 0, stream>>>(CNT, BSUM);
    scan_p2<<<1, 256, 0, stream>>>(BSUM, BPRE, OFF);
    scan_p3<<<SCAN_NB, 256, 0, stream>>>(CNT, BPRE, OFF);
    pos2_kernel<<<N_EDGES/256, 256, 0, stream>>>(dst, OFF, RANK);   // RANK -> P

    edge_mfma3_kernel<<<N_EDGES/64, 256, 0, stream>>>(x, src, RANK, eattr,
                                                      AC1, WHI1, MSG);
    node_gather_kernel<<<(N_NODES*16+255)/256, 256, 0, stream>>>(x, MSG, OFF,
                                                                 root1, bias1, X1);

    edge_mfma3_kernel<<<N_EDGES/64, 256, 0, stream>>>(X1, src, RANK, eattr,
                                                      AC2, WHI2, MSG);
    node_gather_kernel<<<(N_NODES*16+255)/256, 256, 0, stream>>>(X1, MSG, OFF,
                                                                 root2, bias2, X2);

    pool_final_kernel<<<N_GRAPHS, 64, 0, stream>>>(X2, GOFF, fcW, fcb, (float*)d_out);
}

// Round 11
// 277.731 us; speedup vs baseline: 1.3120x; 1.1175x over previous
//
#include <hip/hip_runtime.h>
#include <math.h>

#define N_NODES 50000
#define N_EDGES 800000
#define IN_C 16
#define HID_C 16
#define OUT_C 10
#define N_GRAPHS 500
#define EDGE_DIM 3
#define MLP_HID 25
#define BN_EPS 1e-5f

#define SCAN_NB ((N_NODES + 255) / 256)   // 196 blocks

typedef __attribute__((ext_vector_type(8))) short short8;
typedef __attribute__((ext_vector_type(4))) float f32x4;
typedef __attribute__((ext_vector_type(2))) float f32x2;
union U4S8 { uint4 u; short8 s; };

// ---------------- setup: BN-fold + goff + W-pack in ONE kernel ----------------

// blocks 0..6 : pack W' = [Wb rows (k'=k*16+i, k<25) ; bb rows (k'=400+i)]
//               (416x16) into per-MFMA per-lane bf16 B-fragments (RNE).
//               Element j of (m, lane L): row k'=32m+8(L>>4)+j, col o=L&15.
// block 7     : also folds BN into AC[k][4]={A0,A1,A2,C} (k<25), AC[25]={0,0,0,1}.
// blocks 7..8 : goff[g] = lower_bound(batch, g) (batch sorted).
__global__ __launch_bounds__(256) void setup_kernel(
    const float* __restrict__ W1a, const float* __restrict__ b1a,
    const float* __restrict__ g1, const float* __restrict__ bt1,
    const float* __restrict__ m1, const float* __restrict__ v1,
    const float* __restrict__ W2a, const float* __restrict__ b2a,
    const float* __restrict__ g2, const float* __restrict__ bt2,
    const float* __restrict__ m2, const float* __restrict__ v2,
    const float* __restrict__ W1b, const float* __restrict__ b1b,
    const float* __restrict__ W2b, const float* __restrict__ b2b,
    const int* __restrict__ batch,
    float* __restrict__ AC1, float* __restrict__ AC2,
    unsigned int* __restrict__ WHI1, unsigned int* __restrict__ WHI2,
    int* __restrict__ goff)
{
    const int blk = blockIdx.x;
    const int tid = threadIdx.x;
    if (blk < 7) {
        int t = blk * 256 + tid;
        if (t >= 1664) return;
        const float *Wb, *bb; unsigned int *WH;
        int tl = t;
        if (t < 832) { Wb = W1b; bb = b1b; WH = WHI1; }
        else { tl = t - 832; Wb = W2b; bb = b2b; WH = WHI2; }
        int m = tl >> 6;
        int L = tl & 63;
        int q = L >> 4, o = L & 15;
        unsigned int hi[8];
        for (int j = 0; j < 8; ++j) {
            int kp = m*32 + q*8 + j;          // 0..415
            int k = kp >> 4, i = kp & 15;
            float w = (k < 25) ? Wb[k*256 + i*16 + o] : bb[i*16 + o];
            unsigned int u = __float_as_uint(w);
            hi[j] = (u + 0x7FFFu + ((u >> 16) & 1u)) >> 16;   // bf16 RNE
        }
        int base = (m*64 + L) * 4;
        for (int d = 0; d < 4; ++d)
            WH[base + d] = hi[2*d] | (hi[2*d+1] << 16);
        return;
    }
    if (blk == 7) {
        if (tid < 26) {
            int k = tid;
            if (k < 25) {
                float sc = g1[k] / sqrtf(v1[k] + BN_EPS);
                AC1[k*4+0] = sc * W1a[0*MLP_HID+k];
                AC1[k*4+1] = sc * W1a[1*MLP_HID+k];
                AC1[k*4+2] = sc * W1a[2*MLP_HID+k];
                AC1[k*4+3] = sc * (b1a[k] - m1[k]) + bt1[k];
            } else {
                AC1[100] = 0.f; AC1[101] = 0.f; AC1[102] = 0.f; AC1[103] = 1.f;
            }
        } else if (tid >= 32 && tid < 58) {
            int k = tid - 32;
            if (k < 25) {
                float sc = g2[k] / sqrtf(v2[k] + BN_EPS);
                AC2[k*4+0] = sc * W2a[0*MLP_HID+k];
                AC2[k*4+1] = sc * W2a[1*MLP_HID+k];
                AC2[k*4+2] = sc * W2a[2*MLP_HID+k];
                AC2[k*4+3] = sc * (b2a[k] - m2[k]) + bt2[k];
            } else {
                AC2[100] = 0.f; AC2[101] = 0.f; AC2[102] = 0.f; AC2[103] = 1.f;
            }
        }
    }
    int g = (blk - 7) * 256 + tid;
    if (g <= N_GRAPHS) {
        int lo = 0, hi = N_NODES;
        while (lo < hi) {
            int mid = (lo + hi) >> 1;
            if (batch[mid] < g) lo = mid + 1; else hi = mid;
        }
        goff[g] = lo;
    }
}

// ---------------- CSR build (one atomic pass + parallel scan) ----------------

__global__ __launch_bounds__(256) void rank_kernel(const int* __restrict__ dst,
                                                   int* __restrict__ cnt,
                                                   int* __restrict__ rank) {
    int e = blockIdx.x * blockDim.x + threadIdx.x;
    if (e < N_EDGES) rank[e] = atomicAdd(&cnt[dst[e]], 1);
}

__global__ __launch_bounds__(256) void scan_p1(const int* __restrict__ cnt,
                                               int* __restrict__ bsum) {
    __shared__ int lds[256];
    int t = threadIdx.x;
    int idx = blockIdx.x * 256 + t;
    lds[t] = (idx < N_NODES) ? cnt[idx] : 0;
    __syncthreads();
    for (int d = 128; d > 0; d >>= 1) {
        if (t < d) lds[t] += lds[t + d];
        __syncthreads();
    }
    if (t == 0) bsum[blockIdx.x] = lds[0];
}

__global__ __launch_bounds__(256) void scan_p2(const int* __restrict__ bsum,
                                               int* __restrict__ bpre,
                                               int* __restrict__ off) {
    __shared__ int lds[256];
    int t = threadIdx.x;
    lds[t] = (t < SCAN_NB) ? bsum[t] : 0;
    __syncthreads();
    for (int d = 1; d < 256; d <<= 1) {
        int v = (t >= d) ? lds[t - d] : 0;
        __syncthreads();
        lds[t] += v;
        __syncthreads();
    }
    if (t < SCAN_NB) bpre[t] = (t > 0) ? lds[t - 1] : 0;
    if (t == 255) off[N_NODES] = lds[255];
}

__global__ __launch_bounds__(256) void scan_p3(const int* __restrict__ cnt,
                                               const int* __restrict__ bpre,
                                               int* __restrict__ off) {
    __shared__ int lds[256];
    int t = threadIdx.x;
    int idx = blockIdx.x * 256 + t;
    int v = (idx < N_NODES) ? cnt[idx] : 0;
    lds[t] = v;
    __syncthreads();
    for (int d = 1; d < 256; d <<= 1) {
        int u = (t >= d) ? lds[t - d] : 0;
        __syncthreads();
        lds[t] += u;
        __syncthreads();
    }
    if (idx < N_NODES) off[idx] = bpre[blockIdx.x] + lds[t] - v;
}

// rank[e] <- off[dst[e]] + rank[e]  (in-place: rank becomes the CSR slot P[e])
__global__ __launch_bounds__(256) void pos2_kernel(const int* __restrict__ dst,
                                                   const int* __restrict__ off,
                                                   int* __restrict__ rank) {
    int e = blockIdx.x * blockDim.x + threadIdx.x;
    if (e < N_EDGES) rank[e] = off[dst[e]] + rank[e];
}

// ---------------- hot path: MFMA edge kernel, 2 tiles/wave ----------------

__device__ __forceinline__ U4S8 packH(float h, float4 xl, float4 xh) {
    f32x2 h2; h2.x = h; h2.y = h;
    f32x2 m0; m0.x = xl.x; m0.y = xl.y; m0 *= h2;
    f32x2 m1; m1.x = xl.z; m1.y = xl.w; m1 *= h2;
    f32x2 m2; m2.x = xh.x; m2.y = xh.y; m2 *= h2;
    f32x2 m3; m3.x = xh.z; m3.y = xh.w; m3 *= h2;
    U4S8 r;
    r.u.x = __builtin_amdgcn_perm(__float_as_uint(m0.y), __float_as_uint(m0.x), 0x07060302u);
    r.u.y = __builtin_amdgcn_perm(__float_as_uint(m1.y), __float_as_uint(m1.x), 0x07060302u);
    r.u.z = __builtin_amdgcn_perm(__float_as_uint(m2.y), __float_as_uint(m2.x), 0x07060302u);
    r.u.w = __builtin_amdgcn_perm(__float_as_uint(m3.y), __float_as_uint(m3.x), 0x07060302u);
    return r;
}

// Per wave: 32 edges = 2 tiles of 16, ONE shared WHI load stream. TA-pressure
// analysis (R10): per-lane AC float4 loads were 13 x 1KB/wave broadcast -> AC
// moved to wave-uniform s_load_dwordx8 (rows 2m,2m+1 = 32 contiguous B) +
// per-lane k-select in VALU (6fma+2max+cndmask; VALU has 3x headroom).
// WHI (per-lane fragment, can't be scalar) amortized over 2 tiles. No LDS, no
// barriers; 25k thin waves hide latency by occupancy (R9 lesson: VGPR<=64).
__global__ __launch_bounds__(256) void edge_mfma4_kernel(
    const float* __restrict__ xin,
    const int* __restrict__ src,
    const int* __restrict__ P,
    const float* __restrict__ eattr,
    const float* __restrict__ AC,
    const unsigned int* __restrict__ WHI,
    float* __restrict__ msg_buf)
{
    const int tid  = threadIdx.x;
    const int wave = tid >> 6;
    const int lane = tid & 63;
    const int q    = lane >> 4;
    const int el   = lane & 15;
    const int i0   = (q & 1) * 8;
    const bool bsel = (q >> 1) != 0;
    const int E0   = (blockIdx.x * 4 + wave) * 32;
    const int eA   = E0 + el;
    const int eB   = E0 + 16 + el;

    const int sA = src[eA], sB = src[eB];
    const float aA0 = eattr[(size_t)eA*3+0];
    const float aA1 = eattr[(size_t)eA*3+1];
    const float aA2 = eattr[(size_t)eA*3+2];
    const float aB0 = eattr[(size_t)eB*3+0];
    const float aB1 = eattr[(size_t)eB*3+1];
    const float aB2 = eattr[(size_t)eB*3+2];
    const uint4 ppA = *(const uint4*)(P + E0 + q*4);        // tile A rows q*4+r
    const uint4 ppB = *(const uint4*)(P + E0 + 16 + q*4);   // tile B rows q*4+r
    const float4* xpA = (const float4*)(xin + (size_t)sA*16 + i0);
    const float4 xlA = xpA[0], xhA = xpA[1];
    const float4* xpB = (const float4*)(xin + (size_t)sB*16 + i0);
    const float4 xlB = xpB[0], xhB = xpB[1];

    f32x4 accA = {0.f, 0.f, 0.f, 0.f};
    f32x4 accB = {0.f, 0.f, 0.f, 0.f};
    #pragma unroll 1
    for (int m = 0; m < 13; ++m) {
        // wave-uniform 32B -> s_load_dwordx8 (rows k=2m and k=2m+1)
        const float4 Ae = *(const float4*)(AC + m*8);
        const float4 Ao = *(const float4*)(AC + m*8 + 4);
        U4S8 w; w.u = ((const uint4*)WHI)[m*64 + lane];          // L1-hot
        float hAe = fmaxf(fmaf(aA2, Ae.z, fmaf(aA1, Ae.y, fmaf(aA0, Ae.x, Ae.w))), 0.f);
        float hAo = fmaxf(fmaf(aA2, Ao.z, fmaf(aA1, Ao.y, fmaf(aA0, Ao.x, Ao.w))), 0.f);
        float hA  = bsel ? hAo : hAe;
        float hBe = fmaxf(fmaf(aB2, Ae.z, fmaf(aB1, Ae.y, fmaf(aB0, Ae.x, Ae.w))), 0.f);
        float hBo = fmaxf(fmaf(aB2, Ao.z, fmaf(aB1, Ao.y, fmaf(aB0, Ao.x, Ao.w))), 0.f);
        float hB  = bsel ? hBo : hBe;
        U4S8 hfA = packH(hA, xlA, xhA);
        U4S8 hfB = packH(hB, xlB, xhB);
        accA = __builtin_amdgcn_mfma_f32_16x16x32_bf16(hfA.s, w.s, accA, 0, 0, 0);
        accB = __builtin_amdgcn_mfma_f32_16x16x32_bf16(hfB.s, w.s, accB, 0, 0, 0);
    }

    // D layout: col o = el, row = q*4 + r
    msg_buf[(size_t)((unsigned)ppA.x) * HID_C + el] = accA[0];
    msg_buf[(size_t)((unsigned)ppA.y) * HID_C + el] = accA[1];
    msg_buf[(size_t)((unsigned)ppA.z) * HID_C + el] = accA[2];
    msg_buf[(size_t)((unsigned)ppA.w) * HID_C + el] = accA[3];
    msg_buf[(size_t)((unsigned)ppB.x) * HID_C + el] = accB[0];
    msg_buf[(size_t)((unsigned)ppB.y) * HID_C + el] = accB[1];
    msg_buf[(size_t)((unsigned)ppB.z) * HID_C + el] = accB[2];
    msg_buf[(size_t)((unsigned)ppB.w) * HID_C + el] = accB[3];
}

// 16 threads per node (lane = out channel). Segment-sum msg_buf rows
// [off[n], off[n+1]) -> mean -> + x@root + bias -> ELU.
__global__ __launch_bounds__(256) void node_gather_kernel(
    const float* __restrict__ xin, const float* __restrict__ msg_buf,
    const int* __restrict__ off,
    const float* __restrict__ root, const float* __restrict__ bias,
    float* __restrict__ xout)
{
    int t = blockIdx.x * blockDim.x + threadIdx.x;
    int n = t >> 4;
    int o = t & 15;
    if (n >= N_NODES) return;
    int lo = off[n], hi = off[n+1];
    float inv = 1.f / fmaxf((float)(hi - lo), 1.f);

    float s0 = 0.f, s1 = 0.f, s2 = 0.f, s3 = 0.f;
    int r = lo;
    for (; r + 4 <= hi; r += 4) {
        s0 += msg_buf[(size_t)r     * HID_C + o];
        s1 += msg_buf[(size_t)(r+1) * HID_C + o];
        s2 += msg_buf[(size_t)(r+2) * HID_C + o];
        s3 += msg_buf[(size_t)(r+3) * HID_C + o];
    }
    for (; r < hi; ++r) s0 += msg_buf[(size_t)r * HID_C + o];
    float s = (s0 + s1) + (s2 + s3);

    float acc = fmaf(s, inv, bias[o]);
    const float* xr = xin + (size_t)n * IN_C;
    #pragma unroll
    for (int i = 0; i < IN_C; ++i)
        acc = fmaf(xr[i], root[i*HID_C+o], acc);
    xout[(size_t)n*HID_C + o] = acc > 0.f ? acc : (expf(acc) - 1.f);
}

// fused: global mean pool (batch sorted -> contiguous segments) + final linear
__global__ __launch_bounds__(64) void pool_final_kernel(
    const float* __restrict__ xin, const int* __restrict__ goff,
    const float* __restrict__ fcW, const float* __restrict__ fcb,
    float* __restrict__ out)
{
    __shared__ float part[4][HID_C];
    __shared__ float pooled[HID_C];
    int g = blockIdx.x;
    int t = threadIdx.x;
    int c = t & 15, sub = t >> 4;
    int lo = goff[g], hi = goff[g+1];
    float s = 0.f;
    for (int n = lo + sub; n < hi; n += 4)
        s += xin[(size_t)n*HID_C + c];
    part[sub][c] = s;
    __syncthreads();
    if (t < HID_C) {
        pooled[t] = (part[0][t] + part[1][t] + part[2][t] + part[3][t])
                    / fmaxf((float)(hi - lo), 1.f);
    }
    __syncthreads();
    if (t < OUT_C) {
        float acc = fcb[t];
        #pragma unroll
        for (int i = 0; i < HID_C; ++i)
            acc = fmaf(pooled[i], fcW[i*OUT_C+t], acc);
        out[g*OUT_C + t] = acc;
    }
}

// ---------------- launch ----------------

extern "C" void kernel_launch(void* const* d_in, const int* in_sizes, int n_in,
                              void* d_out, int out_size, void* d_ws, size_t ws_size,
                              hipStream_t stream)
{
    const float* x     = (const float*)d_in[0];
    const int*   ei    = (const int*)d_in[1];
    const float* eattr = (const float*)d_in[2];
    const int*   batch = (const int*)d_in[3];
    const float* W1a   = (const float*)d_in[4];
    const float* b1a   = (const float*)d_in[5];
    const float* g1    = (const float*)d_in[6];
    const float* bt1   = (const float*)d_in[7];
    const float* m1    = (const float*)d_in[8];
    const float* v1    = (const float*)d_in[9];
    const float* W1b   = (const float*)d_in[10];
    const float* b1b   = (const float*)d_in[11];
    const float* root1 = (const float*)d_in[12];
    const float* bias1 = (const float*)d_in[13];
    const float* W2a   = (const float*)d_in[14];
    const float* b2a   = (const float*)d_in[15];
    const float* g2    = (const float*)d_in[16];
    const float* bt2   = (const float*)d_in[17];
    const float* m2    = (const float*)d_in[18];
    const float* v2    = (const float*)d_in[19];
    const float* W2b   = (const float*)d_in[20];
    const float* b2b   = (const float*)d_in[21];
    const float* root2 = (const float*)d_in[22];
    const float* bias2 = (const float*)d_in[23];
    const float* fcW   = (const float*)d_in[24];
    const float* fcb   = (const float*)d_in[25];

    const int* src = ei;
    const int* dst = ei + N_EDGES;

    float* ws   = (float*)d_ws;
    float* MSG  = ws;                                   // 12,800,000 f
    float* X1   = ws + 12800000;                        //    800,000 f
    float* X2   = ws + 13600000;                        //    800,000 f
    int*   RANK = (int*)(ws + 14400000);                //    800,000 i (becomes P)
    int*   CNT  = (int*)(ws + 15200000);                //     50,000 i
    int*   OFF  = (int*)(ws + 15250000);                //     50,001 i (+pad)
    int*   GOFF = (int*)(ws + 15300064);                //        501 i (+pad)
    unsigned int* WHI1 = (unsigned int*)(ws + 15300576);//      3,328 u (16B aligned)
    unsigned int* WHI2 = (unsigned int*)(ws + 15303904);//      3,328 u
    float* AC1  = ws + 15307232;                        //        104 f (+pad)
    float* AC2  = ws + 15307344;                        //        104 f
    int*   BSUM = (int*)(ws + 15307456);                //        196 i (+pad)
    int*   BPRE = (int*)(ws + 15307712);                //        196 i
    // total ~15,307,908 f = 61.23 MB

    hipMemsetAsync(CNT, 0, N_NODES * sizeof(int), stream);
    setup_kernel<<<9, 256, 0, stream>>>(W1a, b1a, g1, bt1, m1, v1,
                                        W2a, b2a, g2, bt2, m2, v2,
                                        W1b, b1b, W2b, b2b, batch,
                                        AC1, AC2, WHI1, WHI2, GOFF);
    rank_kernel<<<N_EDGES/256, 256, 0, stream>>>(dst, CNT, RANK);
    scan_p1<<<SCAN_NB, 256, 0, stream>>>(CNT, BSUM);
    scan_p2<<<1, 256, 0, stream>>>(BSUM, BPRE, OFF);
    scan_p3<<<SCAN_NB, 256, 0, stream>>>(CNT, BPRE, OFF);
    pos2_kernel<<<N_EDGES/256, 256, 0, stream>>>(dst, OFF, RANK);   // RANK -> P

    edge_mfma4_kernel<<<N_EDGES/128, 256, 0, stream>>>(x, src, RANK, eattr,
                                                       AC1, WHI1, MSG);
    node_gather_kernel<<<(N_NODES*16+255)/256, 256, 0, stream>>>(x, MSG, OFF,
                                                                 root1, bias1, X1);

    edge_mfma4_kernel<<<N_EDGES/128, 256, 0, stream>>>(X1, src, RANK, eattr,
                                                       AC2, WHI2, MSG);
    node_gather_kernel<<<(N_NODES*16+255)/256, 256, 0, stream>>>(X1, MSG, OFF,
                                                                 root2, bias2, X2);

    pool_final_kernel<<<N_GRAPHS, 64, 0, stream>>>(X2, GOFF, fcW, fcb, (float*)d_out);
}

// Round 12
// 269.673 us; speedup vs baseline: 1.3512x; 1.0299x over previous
//
#include <hip/hip_runtime.h>
#include <math.h>

#define N_NODES 50000
#define N_EDGES 800000
#define IN_C 16
#define HID_C 16
#define OUT_C 10
#define N_GRAPHS 500
#define EDGE_DIM 3
#define MLP_HID 25
#define BN_EPS 1e-5f

#define SCAN_NB ((N_NODES + 255) / 256)   // 196 blocks

typedef __attribute__((ext_vector_type(8))) _Float16 half8;
typedef __attribute__((ext_vector_type(2))) _Float16 half2v;
typedef __attribute__((ext_vector_type(4))) float f32x4;
union U4H8 { uint4 u; half8 h; half2v p[4]; };
union HU { _Float16 h; unsigned short u; };

// ---------------- setup: W-pack(f16) + BN-fold + goff + zero CNT/ticket ------

// blk 0..6  : pack W' = [Wb rows (k'=k*16+i, k<25) ; bb rows (k'=400+i)]
//             (416x16) into per-MFMA per-lane f16 B-fragments (RNE).
//             Element j of (m, lane L): row k'=32m+8(L>>4)+j, col o=L&15.
// blk 7     : fold BN into AC[k][4]={A0,A1,A2,C} (k<25), AC[25]={0,0,0,1};
// blk 7..8  : goff[g] = lower_bound(batch, g) (batch sorted)
// blk 9..204: zero CNT (and blk9/t0 zeroes the scan ticket)
__global__ __launch_bounds__(256) void setup_kernel(
    const float* __restrict__ W1a, const float* __restrict__ b1a,
    const float* __restrict__ g1, const float* __restrict__ bt1,
    const float* __restrict__ m1, const float* __restrict__ v1,
    const float* __restrict__ W2a, const float* __restrict__ b2a,
    const float* __restrict__ g2, const float* __restrict__ bt2,
    const float* __restrict__ m2, const float* __restrict__ v2,
    const float* __restrict__ W1b, const float* __restrict__ b1b,
    const float* __restrict__ W2b, const float* __restrict__ b2b,
    const int* __restrict__ batch,
    float* __restrict__ AC1, float* __restrict__ AC2,
    unsigned int* __restrict__ WF1, unsigned int* __restrict__ WF2,
    int* __restrict__ goff, int* __restrict__ cnt, int* __restrict__ ticket)
{
    const int blk = blockIdx.x;
    const int tid = threadIdx.x;
    if (blk < 7) {
        int t = blk * 256 + tid;
        if (t >= 1664) return;
        const float *Wb, *bb; unsigned int *WH;
        int tl = t;
        if (t < 832) { Wb = W1b; bb = b1b; WH = WF1; }
        else { tl = t - 832; Wb = W2b; bb = b2b; WH = WF2; }
        int m = tl >> 6;
        int L = tl & 63;
        int q = L >> 4, o = L & 15;
        unsigned int hi[8];
        for (int j = 0; j < 8; ++j) {
            int kp = m*32 + q*8 + j;          // 0..415
            int k = kp >> 4, i = kp & 15;
            float w = (k < 25) ? Wb[k*256 + i*16 + o] : bb[i*16 + o];
            HU cv; cv.h = (_Float16)w;        // f16 RNE
            hi[j] = cv.u;
        }
        int base = (m*64 + L) * 4;
        for (int d = 0; d < 4; ++d)
            WH[base + d] = hi[2*d] | (hi[2*d+1] << 16);
        return;
    }
    if (blk == 7 || blk == 8) {
        if (blk == 7) {
            if (tid < 26) {
                int k = tid;
                if (k < 25) {
                    float sc = g1[k] / sqrtf(v1[k] + BN_EPS);
                    AC1[k*4+0] = sc * W1a[0*MLP_HID+k];
                    AC1[k*4+1] = sc * W1a[1*MLP_HID+k];
                    AC1[k*4+2] = sc * W1a[2*MLP_HID+k];
                    AC1[k*4+3] = sc * (b1a[k] - m1[k]) + bt1[k];
                } else {
                    AC1[100] = 0.f; AC1[101] = 0.f; AC1[102] = 0.f; AC1[103] = 1.f;
                }
            } else if (tid >= 32 && tid < 58) {
                int k = tid - 32;
                if (k < 25) {
                    float sc = g2[k] / sqrtf(v2[k] + BN_EPS);
                    AC2[k*4+0] = sc * W2a[0*MLP_HID+k];
                    AC2[k*4+1] = sc * W2a[1*MLP_HID+k];
                    AC2[k*4+2] = sc * W2a[2*MLP_HID+k];
                    AC2[k*4+3] = sc * (b2a[k] - m2[k]) + bt2[k];
                } else {
                    AC2[100] = 0.f; AC2[101] = 0.f; AC2[102] = 0.f; AC2[103] = 1.f;
                }
            }
        }
        int g = (blk - 7) * 256 + tid;
        if (g <= N_GRAPHS) {
            int lo = 0, hi = N_NODES;
            while (lo < hi) {
                int mid = (lo + hi) >> 1;
                if (batch[mid] < g) lo = mid + 1; else hi = mid;
            }
            goff[g] = lo;
        }
        return;
    }
    // blk 9..204: zero CNT + ticket
    int idx = (blk - 9) * 256 + tid;
    if (idx < N_NODES) cnt[idx] = 0;
    if (blk == 9 && tid == 0) *ticket = 0;
}

// ---------------- CSR build ----------------

__global__ __launch_bounds__(256) void rank_kernel(const int* __restrict__ dst,
                                                   int* __restrict__ cnt,
                                                   int* __restrict__ rank) {
    int e = blockIdx.x * blockDim.x + threadIdx.x;
    if (e < N_EDGES) rank[e] = atomicAdd(&cnt[dst[e]], 1);
}

// phase 1 (+fused phase 2 in the last-arriving block via device-scope ticket):
// per-block sums of cnt; last block scans the 196 block sums -> bpre, total.
__global__ __launch_bounds__(256) void scan_p1(const int* __restrict__ cnt,
                                               int* __restrict__ bsum,
                                               int* __restrict__ bpre,
                                               int* __restrict__ off,
                                               int* __restrict__ ticket) {
    __shared__ int lds[256];
    __shared__ int sDone;
    int t = threadIdx.x;
    int idx = blockIdx.x * 256 + t;
    lds[t] = (idx < N_NODES) ? cnt[idx] : 0;
    __syncthreads();
    for (int d = 128; d > 0; d >>= 1) {
        if (t < d) lds[t] += lds[t + d];
        __syncthreads();
    }
    if (t == 0) {
        bsum[blockIdx.x] = lds[0];
        __threadfence();                       // release bsum
        sDone = atomicAdd(ticket, 1);          // device-scope
    }
    __syncthreads();
    if (sDone != SCAN_NB - 1) return;
    // last block: phase 2
    __threadfence();                           // acquire all bsum
    int v = (t < SCAN_NB) ? bsum[t] : 0;
    __syncthreads();
    lds[t] = v;
    __syncthreads();
    for (int d = 1; d < 256; d <<= 1) {
        int u = (t >= d) ? lds[t - d] : 0;
        __syncthreads();
        lds[t] += u;
        __syncthreads();
    }
    if (t < SCAN_NB) bpre[t] = (t > 0) ? lds[t - 1] : 0;
    if (t == 255) off[N_NODES] = lds[255];
}

// phase 3: per-block exclusive scan + block prefix -> off (coalesced)
__global__ __launch_bounds__(256) void scan_p3(const int* __restrict__ cnt,
                                               const int* __restrict__ bpre,
                                               int* __restrict__ off) {
    __shared__ int lds[256];
    int t = threadIdx.x;
    int idx = blockIdx.x * 256 + t;
    int v = (idx < N_NODES) ? cnt[idx] : 0;
    lds[t] = v;
    __syncthreads();
    for (int d = 1; d < 256; d <<= 1) {
        int u = (t >= d) ? lds[t - d] : 0;
        __syncthreads();
        lds[t] += u;
        __syncthreads();
    }
    if (idx < N_NODES) off[idx] = bpre[blockIdx.x] + lds[t] - v;
}

// ---------------- hot path: f16 MFMA edge kernel, 2 tiles/wave --------------

// Per wave: 32 edges = 2 tiles of 16, one shared WF load stream. f16 path:
// xs converted to f16 RNE ONCE per tile; per-m A-fragment = 4 v_pk_mul_f16
// (replaces R11's 4 pk_mul_f32 + 4 v_perm). h: AC via wave-uniform s_load,
// per-lane parity select-first (4 cndmask) then 3 fma + max. CSR slot p =
// off[dst]+rank recomputed per lane (kills the pos2 dispatch); D-row slots
// for the stores come from 4 __shfl (lane el holds p for edge el).
// No LDS, no barriers; 25k thin waves, VGPR kept low (R9 lesson).
__global__ __launch_bounds__(256) void edge_mfma5_kernel(
    const float* __restrict__ xin,
    const int* __restrict__ src,
    const int* __restrict__ dst,
    const int* __restrict__ rank,
    const int* __restrict__ off,
    const float* __restrict__ eattr,
    const float* __restrict__ AC,
    const unsigned int* __restrict__ WF,
    float* __restrict__ msg_buf)
{
    const int tid  = threadIdx.x;
    const int wave = tid >> 6;
    const int lane = tid & 63;
    const int q    = lane >> 4;
    const int el   = lane & 15;
    const int i0   = (q & 1) * 8;
    const bool bsel = (q >> 1) != 0;
    const int E0   = (blockIdx.x * 4 + wave) * 32;
    const int eA   = E0 + el;
    const int eB   = E0 + 16 + el;

    const int sA = src[eA], sB = src[eB];
    const int pA = off[dst[eA]] + rank[eA];
    const int pB = off[dst[eB]] + rank[eB];
    const float aA0 = eattr[(size_t)eA*3+0];
    const float aA1 = eattr[(size_t)eA*3+1];
    const float aA2 = eattr[(size_t)eA*3+2];
    const float aB0 = eattr[(size_t)eB*3+0];
    const float aB1 = eattr[(size_t)eB*3+1];
    const float aB2 = eattr[(size_t)eB*3+2];
    const float4* xpA = (const float4*)(xin + (size_t)sA*16 + i0);
    const float4 xlA = xpA[0], xhA = xpA[1];
    const float4* xpB = (const float4*)(xin + (size_t)sB*16 + i0);
    const float4 xlB = xpB[0], xhB = xpB[1];

    // xs -> f16 RNE once per tile
    U4H8 xA, xB;
    {
        const float x8A[8] = {xlA.x,xlA.y,xlA.z,xlA.w,xhA.x,xhA.y,xhA.z,xhA.w};
        const float x8B[8] = {xlB.x,xlB.y,xlB.z,xlB.w,xhB.x,xhB.y,xhB.z,xhB.w};
        #pragma unroll
        for (int j = 0; j < 4; ++j) {
            half2v ta; ta.x = (_Float16)x8A[2*j]; ta.y = (_Float16)x8A[2*j+1];
            half2v tb; tb.x = (_Float16)x8B[2*j]; tb.y = (_Float16)x8B[2*j+1];
            xA.p[j] = ta; xB.p[j] = tb;
        }
    }

    f32x4 accA = {0.f, 0.f, 0.f, 0.f};
    f32x4 accB = {0.f, 0.f, 0.f, 0.f};
    #pragma unroll 1
    for (int m = 0; m < 13; ++m) {
        // wave-uniform 32B -> s_load (rows k=2m, 2m+1); per-lane parity select
        const float4 Ae = *(const float4*)(AC + m*8);
        const float4 Ao = *(const float4*)(AC + m*8 + 4);
        const float A0 = bsel ? Ao.x : Ae.x;
        const float A1 = bsel ? Ao.y : Ae.y;
        const float A2 = bsel ? Ao.z : Ae.z;
        const float A3 = bsel ? Ao.w : Ae.w;
        U4H8 w; w.u = ((const uint4*)WF)[m*64 + lane];          // L1-hot
        float hA = fmaxf(fmaf(aA2, A2, fmaf(aA1, A1, fmaf(aA0, A0, A3))), 0.f);
        float hB = fmaxf(fmaf(aB2, A2, fmaf(aB1, A1, fmaf(aB0, A0, A3))), 0.f);
        _Float16 ha = (_Float16)hA, hb = (_Float16)hB;
        half2v hA2; hA2.x = ha; hA2.y = ha;
        half2v hB2; hB2.x = hb; hB2.y = hb;
        U4H8 fA, fB;
        #pragma unroll
        for (int j = 0; j < 4; ++j) {
            fA.p[j] = hA2 * xA.p[j];   // v_pk_mul_f16 -> A-frag directly
            fB.p[j] = hB2 * xB.p[j];
        }
        accA = __builtin_amdgcn_mfma_f32_16x16x32_f16(fA.h, w.h, accA, 0, 0, 0);
        accB = __builtin_amdgcn_mfma_f32_16x16x32_f16(fB.h, w.h, accB, 0, 0, 0);
    }

    // D layout: col o = el, row = q*4 + r; lane el holds p for edge el
    #pragma unroll
    for (int r = 0; r < 4; ++r) {
        int rowA = __shfl(pA, q*4 + r);
        int rowB = __shfl(pB, q*4 + r);
        msg_buf[(size_t)rowA * HID_C + el] = accA[r];
        msg_buf[(size_t)rowB * HID_C + el] = accB[r];
    }
}

// 16 threads per node (lane = out channel). Segment-sum msg_buf rows
// [off[n], off[n+1]) -> mean -> + x@root + bias -> ELU.
__global__ __launch_bounds__(256) void node_gather_kernel(
    const float* __restrict__ xin, const float* __restrict__ msg_buf,
    const int* __restrict__ off,
    const float* __restrict__ root, const float* __restrict__ bias,
    float* __restrict__ xout)
{
    int t = blockIdx.x * blockDim.x + threadIdx.x;
    int n = t >> 4;
    int o = t & 15;
    if (n >= N_NODES) return;
    int lo = off[n], hi = off[n+1];
    float inv = 1.f / fmaxf((float)(hi - lo), 1.f);

    float s0 = 0.f, s1 = 0.f, s2 = 0.f, s3 = 0.f;
    int r = lo;
    for (; r + 4 <= hi; r += 4) {
        s0 += msg_buf[(size_t)r     * HID_C + o];
        s1 += msg_buf[(size_t)(r+1) * HID_C + o];
        s2 += msg_buf[(size_t)(r+2) * HID_C + o];
        s3 += msg_buf[(size_t)(r+3) * HID_C + o];
    }
    for (; r < hi; ++r) s0 += msg_buf[(size_t)r * HID_C + o];
    float s = (s0 + s1) + (s2 + s3);

    float acc = fmaf(s, inv, bias[o]);
    const float* xr = xin + (size_t)n * IN_C;
    #pragma unroll
    for (int i = 0; i < IN_C; ++i)
        acc = fmaf(xr[i], root[i*HID_C+o], acc);
    xout[(size_t)n*HID_C + o] = acc > 0.f ? acc : (expf(acc) - 1.f);
}

// fused: global mean pool (batch sorted -> contiguous segments) + final linear
__global__ __launch_bounds__(64) void pool_final_kernel(
    const float* __restrict__ xin, const int* __restrict__ goff,
    const float* __restrict__ fcW, const float* __restrict__ fcb,
    float* __restrict__ out)
{
    __shared__ float part[4][HID_C];
    __shared__ float pooled[HID_C];
    int g = blockIdx.x;
    int t = threadIdx.x;
    int c = t & 15, sub = t >> 4;
    int lo = goff[g], hi = goff[g+1];
    float s = 0.f;
    for (int n = lo + sub; n < hi; n += 4)
        s += xin[(size_t)n*HID_C + c];
    part[sub][c] = s;
    __syncthreads();
    if (t < HID_C) {
        pooled[t] = (part[0][t] + part[1][t] + part[2][t] + part[3][t])
                    / fmaxf((float)(hi - lo), 1.f);
    }
    __syncthreads();
    if (t < OUT_C) {
        float acc = fcb[t];
        #pragma unroll
        for (int i = 0; i < HID_C; ++i)
            acc = fmaf(pooled[i], fcW[i*OUT_C+t], acc);
        out[g*OUT_C + t] = acc;
    }
}

// ---------------- launch ----------------

extern "C" void kernel_launch(void* const* d_in, const int* in_sizes, int n_in,
                              void* d_out, int out_size, void* d_ws, size_t ws_size,
                              hipStream_t stream)
{
    const float* x     = (const float*)d_in[0];
    const int*   ei    = (const int*)d_in[1];
    const float* eattr = (const float*)d_in[2];
    const int*   batch = (const int*)d_in[3];
    const float* W1a   = (const float*)d_in[4];
    const float* b1a   = (const float*)d_in[5];
    const float* g1    = (const float*)d_in[6];
    const float* bt1   = (const float*)d_in[7];
    const float* m1    = (const float*)d_in[8];
    const float* v1    = (const float*)d_in[9];
    const float* W1b   = (const float*)d_in[10];
    const float* b1b   = (const float*)d_in[11];
    const float* root1 = (const float*)d_in[12];
    const float* bias1 = (const float*)d_in[13];
    const float* W2a   = (const float*)d_in[14];
    const float* b2a   = (const float*)d_in[15];
    const float* g2    = (const float*)d_in[16];
    const float* bt2   = (const float*)d_in[17];
    const float* m2    = (const float*)d_in[18];
    const float* v2    = (const float*)d_in[19];
    const float* W2b   = (const float*)d_in[20];
    const float* b2b   = (const float*)d_in[21];
    const float* root2 = (const float*)d_in[22];
    const float* bias2 = (const float*)d_in[23];
    const float* fcW   = (const float*)d_in[24];
    const float* fcb   = (const float*)d_in[25];

    const int* src = ei;
    const int* dst = ei + N_EDGES;

    float* ws   = (float*)d_ws;
    float* MSG  = ws;                                   // 12,800,000 f
    float* X1   = ws + 12800000;                        //    800,000 f
    float* X2   = ws + 13600000;                        //    800,000 f
    int*   RANK = (int*)(ws + 14400000);                //    800,000 i
    int*   CNT  = (int*)(ws + 15200000);                //     50,000 i
    int*   OFF  = (int*)(ws + 15250000);                //     50,001 i (+pad)
    int*   GOFF = (int*)(ws + 15300064);                //        501 i (+pad)
    unsigned int* WF1 = (unsigned int*)(ws + 15300576); //      3,328 u (16B aligned)
    unsigned int* WF2 = (unsigned int*)(ws + 15303904); //      3,328 u
    float* AC1  = ws + 15307232;                        //        104 f (+pad)
    float* AC2  = ws + 15307344;                        //        104 f
    int*   BSUM = (int*)(ws + 15307456);                //        196 i (+pad)
    int*   BPRE = (int*)(ws + 15307712);                //        196 i (+pad)
    int*   TICK = (int*)(ws + 15307968);                //          1 i
    // total ~15,308,000 f = 61.23 MB

    setup_kernel<<<9 + SCAN_NB, 256, 0, stream>>>(
        W1a, b1a, g1, bt1, m1, v1, W2a, b2a, g2, bt2, m2, v2,
        W1b, b1b, W2b, b2b, batch, AC1, AC2, WF1, WF2, GOFF, CNT, TICK);
    rank_kernel<<<N_EDGES/256, 256, 0, stream>>>(dst, CNT, RANK);
    scan_p1<<<SCAN_NB, 256, 0, stream>>>(CNT, BSUM, BPRE, OFF, TICK);
    scan_p3<<<SCAN_NB, 256, 0, stream>>>(CNT, BPRE, OFF);

    edge_mfma5_kernel<<<N_EDGES/128, 256, 0, stream>>>(x, src, dst, RANK, OFF,
                                                       eattr, AC1, WF1, MSG);
    node_gather_kernel<<<(N_NODES*16+255)/256, 256, 0, stream>>>(x, MSG, OFF,
                                                                 root1, bias1, X1);

    edge_mfma5_kernel<<<N_EDGES/128, 256, 0, stream>>>(X1, src, dst, RANK, OFF,
                                                       eattr, AC2, WF2, MSG);
    node_gather_kernel<<<(N_NODES*16+255)/256, 256, 0, stream>>>(X1, MSG, OFF,
                                                                 root2, bias2, X2);

    pool_final_kernel<<<N_GRAPHS, 64, 0, stream>>>(X2, GOFF, fcW, fcb, (float*)d_out);
}

// Round 13
// 260.479 us; speedup vs baseline: 1.3989x; 1.0353x over previous
//
#include <hip/hip_runtime.h>
#include <math.h>

#define N_NODES 50000
#define N_EDGES 800000
#define IN_C 16
#define HID_C 16
#define OUT_C 10
#define N_GRAPHS 500
#define EDGE_DIM 3
#define MLP_HID 25
#define BN_EPS 1e-5f

#define SCAN_NB ((N_NODES + 255) / 256)   // 196 blocks

typedef __attribute__((ext_vector_type(8))) _Float16 half8;
typedef __attribute__((ext_vector_type(2))) _Float16 half2v;
typedef __attribute__((ext_vector_type(4))) float f32x4;
union U4H8 { uint4 u; half8 h; half2v p[4]; };
union HU { _Float16 h; unsigned short u; };

// ---------------- setup: W-pack(f16) + BN-fold + goff + zero CNT/ticket ------

// blk 0..6  : pack W' = [Wb rows (k'=k*16+i, k<25) ; bb rows (k'=400+i)]
//             (416x16) into per-MFMA per-lane f16 fragments (RNE).
//             Element j of (m, lane L): row k'=32m+8(L>>4)+j, col o=L&15.
//             (Identical data serves as the A-operand W'^T[o][k'] fragment.)
// blk 7     : fold BN into AC[k][4]={A0,A1,A2,C} (k<25), AC[25]={0,0,0,1};
// blk 7..8  : goff[g] = lower_bound(batch, g) (batch sorted)
// blk 9..204: zero CNT (and blk9/t0 zeroes the scan ticket)
__global__ __launch_bounds__(256) void setup_kernel(
    const float* __restrict__ W1a, const float* __restrict__ b1a,
    const float* __restrict__ g1, const float* __restrict__ bt1,
    const float* __restrict__ m1, const float* __restrict__ v1,
    const float* __restrict__ W2a, const float* __restrict__ b2a,
    const float* __restrict__ g2, const float* __restrict__ bt2,
    const float* __restrict__ m2, const float* __restrict__ v2,
    const float* __restrict__ W1b, const float* __restrict__ b1b,
    const float* __restrict__ W2b, const float* __restrict__ b2b,
    const int* __restrict__ batch,
    float* __restrict__ AC1, float* __restrict__ AC2,
    unsigned int* __restrict__ WF1, unsigned int* __restrict__ WF2,
    int* __restrict__ goff, int* __restrict__ cnt, int* __restrict__ ticket)
{
    const int blk = blockIdx.x;
    const int tid = threadIdx.x;
    if (blk < 7) {
        int t = blk * 256 + tid;
        if (t >= 1664) return;
        const float *Wb, *bb; unsigned int *WH;
        int tl = t;
        if (t < 832) { Wb = W1b; bb = b1b; WH = WF1; }
        else { tl = t - 832; Wb = W2b; bb = b2b; WH = WF2; }
        int m = tl >> 6;
        int L = tl & 63;
        int q = L >> 4, o = L & 15;
        unsigned int hi[8];
        for (int j = 0; j < 8; ++j) {
            int kp = m*32 + q*8 + j;          // 0..415
            int k = kp >> 4, i = kp & 15;
            float w = (k < 25) ? Wb[k*256 + i*16 + o] : bb[i*16 + o];
            HU cv; cv.h = (_Float16)w;        // f16 RNE
            hi[j] = cv.u;
        }
        int base = (m*64 + L) * 4;
        for (int d = 0; d < 4; ++d)
            WH[base + d] = hi[2*d] | (hi[2*d+1] << 16);
        return;
    }
    if (blk == 7 || blk == 8) {
        if (blk == 7) {
            if (tid < 26) {
                int k = tid;
                if (k < 25) {
                    float sc = g1[k] / sqrtf(v1[k] + BN_EPS);
                    AC1[k*4+0] = sc * W1a[0*MLP_HID+k];
                    AC1[k*4+1] = sc * W1a[1*MLP_HID+k];
                    AC1[k*4+2] = sc * W1a[2*MLP_HID+k];
                    AC1[k*4+3] = sc * (b1a[k] - m1[k]) + bt1[k];
                } else {
                    AC1[100] = 0.f; AC1[101] = 0.f; AC1[102] = 0.f; AC1[103] = 1.f;
                }
            } else if (tid >= 32 && tid < 58) {
                int k = tid - 32;
                if (k < 25) {
                    float sc = g2[k] / sqrtf(v2[k] + BN_EPS);
                    AC2[k*4+0] = sc * W2a[0*MLP_HID+k];
                    AC2[k*4+1] = sc * W2a[1*MLP_HID+k];
                    AC2[k*4+2] = sc * W2a[2*MLP_HID+k];
                    AC2[k*4+3] = sc * (b2a[k] - m2[k]) + bt2[k];
                } else {
                    AC2[100] = 0.f; AC2[101] = 0.f; AC2[102] = 0.f; AC2[103] = 1.f;
                }
            }
        }
        int g = (blk - 7) * 256 + tid;
        if (g <= N_GRAPHS) {
            int lo = 0, hi = N_NODES;
            while (lo < hi) {
                int mid = (lo + hi) >> 1;
                if (batch[mid] < g) lo = mid + 1; else hi = mid;
            }
            goff[g] = lo;
        }
        return;
    }
    int idx = (blk - 9) * 256 + tid;
    if (idx < N_NODES) cnt[idx] = 0;
    if (blk == 9 && tid == 0) *ticket = 0;
}

// ---------------- CSR build ----------------

__global__ __launch_bounds__(256) void rank_kernel(const int* __restrict__ dst,
                                                   int* __restrict__ cnt,
                                                   int* __restrict__ rank) {
    int e = blockIdx.x * blockDim.x + threadIdx.x;
    if (e < N_EDGES) rank[e] = atomicAdd(&cnt[dst[e]], 1);
}

// phase 1 (+fused phase 2 in the last-arriving block via device-scope ticket)
__global__ __launch_bounds__(256) void scan_p1(const int* __restrict__ cnt,
                                               int* __restrict__ bsum,
                                               int* __restrict__ bpre,
                                               int* __restrict__ off,
                                               int* __restrict__ ticket) {
    __shared__ int lds[256];
    __shared__ int sDone;
    int t = threadIdx.x;
    int idx = blockIdx.x * 256 + t;
    lds[t] = (idx < N_NODES) ? cnt[idx] : 0;
    __syncthreads();
    for (int d = 128; d > 0; d >>= 1) {
        if (t < d) lds[t] += lds[t + d];
        __syncthreads();
    }
    if (t == 0) {
        bsum[blockIdx.x] = lds[0];
        __threadfence();
        sDone = atomicAdd(ticket, 1);
    }
    __syncthreads();
    if (sDone != SCAN_NB - 1) return;
    __threadfence();
    int v = (t < SCAN_NB) ? bsum[t] : 0;
    __syncthreads();
    lds[t] = v;
    __syncthreads();
    for (int d = 1; d < 256; d <<= 1) {
        int u = (t >= d) ? lds[t - d] : 0;
        __syncthreads();
        lds[t] += u;
        __syncthreads();
    }
    if (t < SCAN_NB) bpre[t] = (t > 0) ? lds[t - 1] : 0;
    if (t == 255) off[N_NODES] = lds[255];
}

__global__ __launch_bounds__(256) void scan_p3(const int* __restrict__ cnt,
                                               const int* __restrict__ bpre,
                                               int* __restrict__ off) {
    __shared__ int lds[256];
    int t = threadIdx.x;
    int idx = blockIdx.x * 256 + t;
    int v = (idx < N_NODES) ? cnt[idx] : 0;
    lds[t] = v;
    __syncthreads();
    for (int d = 1; d < 256; d <<= 1) {
        int u = (t >= d) ? lds[t - d] : 0;
        __syncthreads();
        lds[t] += u;
        __syncthreads();
    }
    if (idx < N_NODES) off[idx] = bpre[blockIdx.x] + lds[t] - v;
}

// ---------------- hot path: f16 MFMA edge kernel, 4 tiles/wave --------------

// Per wave: 64 edges = 4 tiles of 16. TA-instruction diet (R10/R12 analysis:
// the kernel is VMEM-ISSUE bound, ~16cyc TA per instr):
//  - WF fragments staged in LDS once per BLOCK (13 VMEM/block; in-loop reads
//    move to the idle LDS pipe as ds_read_b128).
//  - MFMA operands SWAPPED: mfma(w, h, acc) computes msg^T. A/B fragments
//    share the same (lane,elem) mapping on 16x16x32, so the packed data is
//    unchanged, but lane (q,el) now holds msg[edge el][o=q*4..+3] = 16
//    contiguous bytes -> ONE dwordx4 store per tile.
//  - src/dst/rank as 3 coalesced dwords (lane<->edge) + 1 off-gather;
//    per-tile values distributed via __shfl (LDS-pipe bpermute).
// ~31 VMEM instr / 64 edges (was ~39/32). No barriers after preamble.
__global__ __launch_bounds__(256) void edge_mfma6_kernel(
    const float* __restrict__ xin,
    const int* __restrict__ src,
    const int* __restrict__ dst,
    const int* __restrict__ rank,
    const int* __restrict__ off,
    const float* __restrict__ eattr,
    const float* __restrict__ AC,
    const unsigned int* __restrict__ WF,
    float* __restrict__ msg_buf)
{
    __shared__ uint4 wf_s[832];                         // 13312 B
    const int tid = threadIdx.x;
    #pragma unroll
    for (int it = 0; it < 4; ++it) {
        int gi = tid + it*256;
        if (gi < 832) wf_s[gi] = ((const uint4*)WF)[gi];
    }
    __syncthreads();

    const int wave = tid >> 6;
    const int lane = tid & 63;
    const int q    = lane >> 4;
    const int el   = lane & 15;
    const int i0   = (q & 1) * 8;
    const bool bsel = (q >> 1) != 0;
    const int E0   = (blockIdx.x * 4 + wave) * 64;

    // coalesced scalar plane: lane L <-> edge E0+L
    const int sAll = src[E0 + lane];
    const int dAll = dst[E0 + lane];
    const int rAll = rank[E0 + lane];
    const int pAll = off[dAll] + rAll;     // CSR slot of edge E0+lane

    // per-tile src via shuffle; eattr per-lane (3 dwords/tile)
    int   sT[4];
    float a0[4], a1[4], a2[4];
    #pragma unroll
    for (int t = 0; t < 4; ++t) {
        sT[t] = __shfl(sAll, t*16 + el);
        int e = E0 + t*16 + el;
        a0[t] = eattr[(size_t)e*3+0];
        a1[t] = eattr[(size_t)e*3+1];
        a2[t] = eattr[(size_t)e*3+2];
    }

    // xs gather + f16 RNE once per tile
    U4H8 xf[4];
    #pragma unroll
    for (int t = 0; t < 4; ++t) {
        const float4* xp = (const float4*)(xin + (size_t)sT[t]*16 + i0);
        const float4 xl = xp[0], xh = xp[1];
        const float x8[8] = {xl.x,xl.y,xl.z,xl.w,xh.x,xh.y,xh.z,xh.w};
        #pragma unroll
        for (int j = 0; j < 4; ++j) {
            half2v tv; tv.x = (_Float16)x8[2*j]; tv.y = (_Float16)x8[2*j+1];
            xf[t].p[j] = tv;
        }
    }

    f32x4 acc0 = {0.f,0.f,0.f,0.f}, acc1 = {0.f,0.f,0.f,0.f};
    f32x4 acc2 = {0.f,0.f,0.f,0.f}, acc3 = {0.f,0.f,0.f,0.f};
    #pragma unroll 1
    for (int m = 0; m < 13; ++m) {
        // wave-uniform s_load of AC rows 2m, 2m+1; per-lane parity select
        const float4 Ae = *(const float4*)(AC + m*8);
        const float4 Ao = *(const float4*)(AC + m*8 + 4);
        const float A0 = bsel ? Ao.x : Ae.x;
        const float A1 = bsel ? Ao.y : Ae.y;
        const float A2 = bsel ? Ao.z : Ae.z;
        const float A3 = bsel ? Ao.w : Ae.w;
        U4H8 w; w.u = wf_s[m*64 + lane];     // ds_read_b128 (LDS pipe)
        #pragma unroll
        for (int t = 0; t < 4; ++t) {
            float h = fmaxf(fmaf(a2[t], A2, fmaf(a1[t], A1,
                              fmaf(a0[t], A0, A3))), 0.f);
            _Float16 hh = (_Float16)h;
            half2v h2; h2.x = hh; h2.y = hh;
            U4H8 f;
            #pragma unroll
            for (int j = 0; j < 4; ++j) f.p[j] = h2 * xf[t].p[j];
            // swapped operands: D = W'^T @ H^T = msg^T
            f32x4 a = (t==0) ? acc0 : (t==1) ? acc1 : (t==2) ? acc2 : acc3;
            a = __builtin_amdgcn_mfma_f32_16x16x32_f16(w.h, f.h, a, 0, 0, 0);
            if (t==0) acc0 = a; else if (t==1) acc1 = a;
            else if (t==2) acc2 = a; else acc3 = a;
        }
    }

    // lane (q,el) holds msg[edge el][o=q*4..q*4+3] -> one dwordx4 per tile
    #pragma unroll
    for (int t = 0; t < 4; ++t) {
        int row = __shfl(pAll, t*16 + el);
        f32x4 a = (t==0) ? acc0 : (t==1) ? acc1 : (t==2) ? acc2 : acc3;
        *(f32x4*)(msg_buf + (size_t)row * HID_C + q*4) = a;
    }
}

// 16 threads per node (lane = out channel). Segment-sum msg_buf rows
// [off[n], off[n+1]) -> mean -> + x@root + bias -> ELU.
__global__ __launch_bounds__(256) void node_gather_kernel(
    const float* __restrict__ xin, const float* __restrict__ msg_buf,
    const int* __restrict__ off,
    const float* __restrict__ root, const float* __restrict__ bias,
    float* __restrict__ xout)
{
    int t = blockIdx.x * blockDim.x + threadIdx.x;
    int n = t >> 4;
    int o = t & 15;
    if (n >= N_NODES) return;
    int lo = off[n], hi = off[n+1];
    float inv = 1.f / fmaxf((float)(hi - lo), 1.f);

    float s0 = 0.f, s1 = 0.f, s2 = 0.f, s3 = 0.f;
    int r = lo;
    for (; r + 4 <= hi; r += 4) {
        s0 += msg_buf[(size_t)r     * HID_C + o];
        s1 += msg_buf[(size_t)(r+1) * HID_C + o];
        s2 += msg_buf[(size_t)(r+2) * HID_C + o];
        s3 += msg_buf[(size_t)(r+3) * HID_C + o];
    }
    for (; r < hi; ++r) s0 += msg_buf[(size_t)r * HID_C + o];
    float s = (s0 + s1) + (s2 + s3);

    float acc = fmaf(s, inv, bias[o]);
    const float* xr = xin + (size_t)n * IN_C;
    #pragma unroll
    for (int i = 0; i < IN_C; ++i)
        acc = fmaf(xr[i], root[i*HID_C+o], acc);
    xout[(size_t)n*HID_C + o] = acc > 0.f ? acc : (expf(acc) - 1.f);
}

// fused: global mean pool (batch sorted -> contiguous segments) + final linear
__global__ __launch_bounds__(64) void pool_final_kernel(
    const float* __restrict__ xin, const int* __restrict__ goff,
    const float* __restrict__ fcW, const float* __restrict__ fcb,
    float* __restrict__ out)
{
    __shared__ float part[4][HID_C];
    __shared__ float pooled[HID_C];
    int g = blockIdx.x;
    int t = threadIdx.x;
    int c = t & 15, sub = t >> 4;
    int lo = goff[g], hi = goff[g+1];
    float s = 0.f;
    for (int n = lo + sub; n < hi; n += 4)
        s += xin[(size_t)n*HID_C + c];
    part[sub][c] = s;
    __syncthreads();
    if (t < HID_C) {
        pooled[t] = (part[0][t] + part[1][t] + part[2][t] + part[3][t])
                    / fmaxf((float)(hi - lo), 1.f);
    }
    __syncthreads();
    if (t < OUT_C) {
        float acc = fcb[t];
        #pragma unroll
        for (int i = 0; i < HID_C; ++i)
            acc = fmaf(pooled[i], fcW[i*OUT_C+t], acc);
        out[g*OUT_C + t] = acc;
    }
}

// ---------------- launch ----------------

extern "C" void kernel_launch(void* const* d_in, const int* in_sizes, int n_in,
                              void* d_out, int out_size, void* d_ws, size_t ws_size,
                              hipStream_t stream)
{
    const float* x     = (const float*)d_in[0];
    const int*   ei    = (const int*)d_in[1];
    const float* eattr = (const float*)d_in[2];
    const int*   batch = (const int*)d_in[3];
    const float* W1a   = (const float*)d_in[4];
    const float* b1a   = (const float*)d_in[5];
    const float* g1    = (const float*)d_in[6];
    const float* bt1   = (const float*)d_in[7];
    const float* m1    = (const float*)d_in[8];
    const float* v1    = (const float*)d_in[9];
    const float* W1b   = (const float*)d_in[10];
    const float* b1b   = (const float*)d_in[11];
    const float* root1 = (const float*)d_in[12];
    const float* bias1 = (const float*)d_in[13];
    const float* W2a   = (const float*)d_in[14];
    const float* b2a   = (const float*)d_in[15];
    const float* g2    = (const float*)d_in[16];
    const float* bt2   = (const float*)d_in[17];
    const float* m2    = (const float*)d_in[18];
    const float* v2    = (const float*)d_in[19];
    const float* W2b   = (const float*)d_in[20];
    const float* b2b   = (const float*)d_in[21];
    const float* root2 = (const float*)d_in[22];
    const float* bias2 = (const float*)d_in[23];
    const float* fcW   = (const float*)d_in[24];
    const float* fcb   = (const float*)d_in[25];

    const int* src = ei;
    const int* dst = ei + N_EDGES;

    float* ws   = (float*)d_ws;
    float* MSG  = ws;                                   // 12,800,000 f
    float* X1   = ws + 12800000;                        //    800,000 f
    float* X2   = ws + 13600000;                        //    800,000 f
    int*   RANK = (int*)(ws + 14400000);                //    800,000 i
    int*   CNT  = (int*)(ws + 15200000);                //     50,000 i
    int*   OFF  = (int*)(ws + 15250000);                //     50,001 i (+pad)
    int*   GOFF = (int*)(ws + 15300064);                //        501 i (+pad)
    unsigned int* WF1 = (unsigned int*)(ws + 15300576); //      3,328 u (16B aligned)
    unsigned int* WF2 = (unsigned int*)(ws + 15303904); //      3,328 u
    float* AC1  = ws + 15307232;                        //        104 f (+pad)
    float* AC2  = ws + 15307344;                        //        104 f
    int*   BSUM = (int*)(ws + 15307456);                //        196 i (+pad)
    int*   BPRE = (int*)(ws + 15307712);                //        196 i (+pad)
    int*   TICK = (int*)(ws + 15307968);                //          1 i
    // total ~15,308,000 f = 61.23 MB

    setup_kernel<<<9 + SCAN_NB, 256, 0, stream>>>(
        W1a, b1a, g1, bt1, m1, v1, W2a, b2a, g2, bt2, m2, v2,
        W1b, b1b, W2b, b2b, batch, AC1, AC2, WF1, WF2, GOFF, CNT, TICK);
    rank_kernel<<<N_EDGES/256, 256, 0, stream>>>(dst, CNT, RANK);
    scan_p1<<<SCAN_NB, 256, 0, stream>>>(CNT, BSUM, BPRE, OFF, TICK);
    scan_p3<<<SCAN_NB, 256, 0, stream>>>(CNT, BPRE, OFF);

    edge_mfma6_kernel<<<N_EDGES/256, 256, 0, stream>>>(x, src, dst, RANK, OFF,
                                                       eattr, AC1, WF1, MSG);
    node_gather_kernel<<<(N_NODES*16+255)/256, 256, 0, stream>>>(x, MSG, OFF,
                                                                 root1, bias1, X1);

    edge_mfma6_kernel<<<N_EDGES/256, 256, 0, stream>>>(X1, src, dst, RANK, OFF,
                                                       eattr, AC2, WF2, MSG);
    node_gather_kernel<<<(N_NODES*16+255)/256, 256, 0, stream>>>(X1, MSG, OFF,
                                                                 root2, bias2, X2);

    pool_final_kernel<<<N_GRAPHS, 64, 0, stream>>>(X2, GOFF, fcW, fcb, (float*)d_out);
}